// Round 7
// baseline (383.674 us; speedup 1.0000x reference)
//
#include <hip/hip_runtime.h>

// Shapes: B=4, C=16, D=16, W=32, DM=512, H=8, HD=64. 1024 slabs of 32 tokens.
// Sequence (b,h,c',d') <-> slab (b, c=2h+(c'>>3), d=2(c'&7)+(d'>>3)), j=d'&7:
//   tokens w = 4j..4j+3; position w' = (w&3)*8 + t uses qkv cols [t*192, t*192+192).
// vhat inverse: token (c,d,w), dm = t*64 + e from position w'=(w&3)*8+t of seq j=w>>2.
//
// R2: bf16 -> fp16 (absmax 0.0322 -> 0.0039, passes).
// R3: Occ 11.8% (1 wave/SIMD), MfmaUtil 8%, HBM 4.6% -> latency-bound.
// R4/R5: 512 threads -> Occ 23%, but only 355->300us; VGPR=88 shows the compiler
//        collapsed the depth-2 prefetch (loads sunk to uses, full L3-class stalls).
// R6/R7: quarter-chunk double-buffered weight staging in registers (wb[2][16], fully
//     unrolled, static idx), per-nf base ptrs (loads = base + imm offset),
//     launch_bounds(512,2) to cap VGPR at 256; nt loads on x / nt stores on out
//     so the per-block 128KB streams stop evicting the 2MB weight set from L2.
//     (R7: nt loads via ext_vector_type ptr — builtin rejects HIP_vector_type.)

using f16x8 = __attribute__((ext_vector_type(8))) _Float16;
using f32x4 = __attribute__((ext_vector_type(4))) float;
using u16x4 = __attribute__((ext_vector_type(4))) unsigned short;

#define DEVI static __device__ __forceinline__

DEVI unsigned short f2h(float x) {            // fp32 -> fp16 RNE (v_cvt_f16_f32)
  _Float16 h = (_Float16)x;
  return *(unsigned short*)&h;
}

#define MFMA16(a, b, c) __builtin_amdgcn_mfma_f32_16x16x32_f16((a), (b), (c), 0, 0, 0)

// -------- weight prep: LDS-tiled 64x64 transpose, fp32 -> fp16 [N][K] --------
// 192 blocks for Wqkv (8 kt x 24 nt) + 64 blocks for Wout (8 x 8). 512 threads.
__global__ void __launch_bounds__(512, 1)
prep_w(const float* __restrict__ Wqkv, const float* __restrict__ Wout,
       unsigned short* __restrict__ wq, unsigned short* __restrict__ wo)
{
  __shared__ float t[64][68];
  const int tid = threadIdx.x;
  const int b = blockIdx.x;
  const float* src; unsigned short* dst; int ldsrc, kt, nt;
  if (b < 192) { kt = b / 24; nt = b % 24; src = Wqkv; dst = wq; ldsrc = 1536; }
  else { int b2 = b - 192; kt = b2 >> 3; nt = b2 & 7; src = Wout; dst = wo; ldsrc = 512; }
  const int r = tid >> 4, c4 = (tid & 15) * 4;   // r: 0..31
  #pragma unroll
  for (int it = 0; it < 2; ++it) {          // coalesced float4 reads
    int row = it * 32 + r;
    f32x4 v = *(const f32x4*)&src[(size_t)(kt * 64 + row) * ldsrc + nt * 64 + c4];
    *(f32x4*)&t[row][c4] = v;
  }
  __syncthreads();
  #pragma unroll
  for (int it = 0; it < 2; ++it) {          // coalesced 8B fp16 writes (128B/row)
    int n = it * 32 + r;
    u16x4 o;
    o.x = f2h(t[c4 + 0][n]); o.y = f2h(t[c4 + 1][n]);
    o.z = f2h(t[c4 + 2][n]); o.w = f2h(t[c4 + 3][n]);
    *(u16x4*)&dst[(size_t)(nt * 64 + n) * 512 + kt * 64 + c4] = o;
  }
}

// ---------------- fused LN + QKV + attention + out-proj ----------------
// LDS: qs/ks [seq][pos][72] (pad -> bank spread, 16B-aligned rows),
// vts [seq][e][48] (v transposed for PV B-operand), xv = union(xs, vh) [32][520].
struct __align__(16) SMem {
  unsigned short qs[8][32][72];   // 36864 B
  unsigned short ks[8][32][72];   // 36864 B
  unsigned short vts[8][64][48];  // 49152 B
  unsigned short xv[32][520];     // 33280 B  (xs during QKV, vh during out-proj)
};
static_assert(sizeof(SMem) == 156160, "LDS size");

__global__ void __launch_bounds__(512, 2)
fused_attn(const float* __restrict__ x, const float* __restrict__ gamma,
           const float* __restrict__ beta,
           const unsigned short* __restrict__ wq,   // [1536][512] fp16 (= W_qkv^T)
           const unsigned short* __restrict__ wo,   // [512][512]  fp16 (= W_out^T)
           const float* __restrict__ bout, float* __restrict__ out)
{
  __shared__ SMem sm;
  const int tid = threadIdx.x;
  const int wv  = tid >> 6;        // wave 0..7
  const int ln  = tid & 63;
  const int l15 = ln & 15;
  const int lg  = ln >> 4;         // lane group 0..3
  const size_t slab = blockIdx.x;  // ((b*16)+c)*16+d
  const float* xblk = x + slab * (32 * 512);
  const f32x4 zz = {0.f, 0.f, 0.f, 0.f};

  // ---- Phase 1: LayerNorm -> xs (fp16), 4 tokens per wave, nt loads ----
  {
    const f32x4* gp = (const f32x4*)gamma;
    const f32x4* bp = (const f32x4*)beta;
    f32x4 g0 = gp[ln], g1 = gp[64 + ln];
    f32x4 b0 = bp[ln], b1 = bp[64 + ln];
    f32x4 v[8];
    #pragma unroll
    for (int i = 0; i < 4; ++i) {          // all 8 loads in flight first
      const f32x4* xp = (const f32x4*)(xblk + (wv * 4 + i) * 512);
      v[2 * i]     = __builtin_nontemporal_load(xp + ln);
      v[2 * i + 1] = __builtin_nontemporal_load(xp + 64 + ln);
    }
    #pragma unroll
    for (int i = 0; i < 4; ++i) {
      int w = wv * 4 + i;
      f32x4 v0 = v[2 * i], v1 = v[2 * i + 1];
      float s  = v0.x + v0.y + v0.z + v0.w + v1.x + v1.y + v1.z + v1.w;
      float s2 = v0.x*v0.x + v0.y*v0.y + v0.z*v0.z + v0.w*v0.w
               + v1.x*v1.x + v1.y*v1.y + v1.z*v1.z + v1.w*v1.w;
      #pragma unroll
      for (int d2 = 1; d2 < 64; d2 <<= 1) {
        s  += __shfl_xor(s, d2);
        s2 += __shfl_xor(s2, d2);
      }
      float mean = s * (1.f / 512.f);
      float var  = s2 * (1.f / 512.f) - mean * mean;
      float rstd = rsqrtf(var + 1e-5f);
      u16x4 o0, o1;
      o0.x = f2h((v0.x - mean) * rstd * g0.x + b0.x);
      o0.y = f2h((v0.y - mean) * rstd * g0.y + b0.y);
      o0.z = f2h((v0.z - mean) * rstd * g0.z + b0.z);
      o0.w = f2h((v0.w - mean) * rstd * g0.w + b0.w);
      o1.x = f2h((v1.x - mean) * rstd * g1.x + b1.x);
      o1.y = f2h((v1.y - mean) * rstd * g1.y + b1.y);
      o1.z = f2h((v1.z - mean) * rstd * g1.z + b1.z);
      o1.w = f2h((v1.w - mean) * rstd * g1.w + b1.w);
      *(u16x4*)&sm.xv[w][ln * 4]       = o0;
      *(u16x4*)&sm.xv[w][256 + ln * 4] = o1;
    }
  }
  __syncthreads();

  // ---- Phase 2: QKV GEMM, 192 cols/wave in 3 chunks of 64 ----
  // quarter-chunk (4 k-steps) double-buffered register staging of W
  for (int c = 0; c < 3; ++c) {
    const int nb = wv * 192 + c * 64;
    const _Float16* wr[4];
    #pragma unroll
    for (int nf = 0; nf < 4; ++nf)
      wr[nf] = (const _Float16*)&wq[(size_t)(nb + nf * 16 + l15) * 512 + lg * 8];
    f32x4 acc[2][4];
    #pragma unroll
    for (int a_ = 0; a_ < 2; ++a_)
      #pragma unroll
      for (int b_ = 0; b_ < 4; ++b_) acc[a_][b_] = zz;
    f16x8 wb[2][16];
    #pragma unroll
    for (int kk = 0; kk < 4; ++kk)
      #pragma unroll
      for (int nf = 0; nf < 4; ++nf)
        wb[0][kk * 4 + nf] = *(const f16x8*)(wr[nf] + kk * 32);
    #pragma unroll
    for (int qq = 0; qq < 4; ++qq) {
      if (qq < 3) {                          // prefetch next quarter into other buf
        #pragma unroll
        for (int kk = 0; kk < 4; ++kk)
          #pragma unroll
          for (int nf = 0; nf < 4; ++nf)
            wb[(qq + 1) & 1][kk * 4 + nf] =
              *(const f16x8*)(wr[nf] + (qq + 1) * 128 + kk * 32);
      }
      #pragma unroll
      for (int kk = 0; kk < 4; ++kk) {
        const int k = qq * 4 + kk;
        f16x8 a0 = *(const f16x8*)&sm.xv[l15][k * 32 + lg * 8];
        f16x8 a1 = *(const f16x8*)&sm.xv[l15 + 16][k * 32 + lg * 8];
        #pragma unroll
        for (int nf = 0; nf < 4; ++nf) {
          acc[0][nf] = MFMA16(a0, wb[qq & 1][kk * 4 + nf], acc[0][nf]);
          acc[1][nf] = MFMA16(a1, wb[qq & 1][kk * 4 + nf], acc[1][nf]);
        }
      }
    }
    // epilogue: scatter D frags (col = l15, rows = lg*4+r+16*mf) into qs/ks/vts
    #pragma unroll
    for (int mf = 0; mf < 2; ++mf) {
      #pragma unroll
      for (int nf = 0; nf < 4; ++nf) {
        const int n = nb + nf * 16 + l15;
        const int t = n / 192;
        const int off = n - t * 192;            // frag's 16 cols never cross a 64-seg
        const int sq = lg + 4 * mf;             // seq = w>>2, w = lg*4+r+16*mf
        #pragma unroll
        for (int r = 0; r < 4; ++r) {
          const unsigned short bv = f2h(acc[mf][nf][r]);
          const int pos = r * 8 + t;            // w&3 == r
          if (off < 64)       sm.qs[sq][pos][off]            = bv;
          else if (off < 128) sm.ks[sq][pos][off - 64]       = bv;
          else                sm.vts[sq][off - 128][pos]     = bv;
        }
      }
    }
  }
  __syncthreads();

  // ---- Phase 3: attention, 1 sequence per wave ----
  {
    const int sq = wv;
    unsigned short* ps = &sm.qs[sq][0][0];      // [32][40] overlay on dead q-buffer
    const unsigned short* qb = &sm.qs[sq][0][0];
    const unsigned short* kb = &sm.ks[sq][0][0];
    const unsigned short* vb = &sm.vts[sq][0][0];
    f32x4 sc[2][2] = {{zz, zz}, {zz, zz}};
    #pragma unroll
    for (int k2 = 0; k2 < 2; ++k2) {            // K=64 over e
      f16x8 a0 = *(const f16x8*)&qb[l15 * 72 + k2 * 32 + lg * 8];
      f16x8 a1 = *(const f16x8*)&qb[(l15 + 16) * 72 + k2 * 32 + lg * 8];
      f16x8 b0 = *(const f16x8*)&kb[l15 * 72 + k2 * 32 + lg * 8];
      f16x8 b1 = *(const f16x8*)&kb[(l15 + 16) * 72 + k2 * 32 + lg * 8];
      sc[0][0] = MFMA16(a0, b0, sc[0][0]);
      sc[0][1] = MFMA16(a0, b1, sc[0][1]);
      sc[1][0] = MFMA16(a1, b0, sc[1][0]);
      sc[1][1] = MFMA16(a1, b1, sc[1][1]);
    }
    // softmax over 32 cols; row r lives in one 16-lane group (cols l15, l15+16)
    #pragma unroll
    for (int mf = 0; mf < 2; ++mf) {
      #pragma unroll
      for (int r = 0; r < 4; ++r) {
        float s0 = sc[mf][0][r] * 8.f;          // reference MULTIPLIES by sqrt(64)
        float s1 = sc[mf][1][r] * 8.f;
        float m = fmaxf(s0, s1);
        #pragma unroll
        for (int d2 = 1; d2 < 16; d2 <<= 1) m = fmaxf(m, __shfl_xor(m, d2));
        float p0 = expf(s0 - m), p1 = expf(s1 - m);
        float sum = p0 + p1;
        #pragma unroll
        for (int d2 = 1; d2 < 16; d2 <<= 1) sum += __shfl_xor(sum, d2);
        float inv = 1.f / sum;
        const int row = lg * 4 + r + 16 * mf;
        ps[row * 40 + l15]      = f2h(p0 * inv);
        ps[row * 40 + l15 + 16] = f2h(p1 * inv);
      }
    }
    // PV: A = P (via LDS transpose), B = V^T rows -> 16B contiguous reads
    f32x4 ov[2][4] = {{zz, zz, zz, zz}, {zz, zz, zz, zz}};
    f16x8 pa0 = *(const f16x8*)&ps[l15 * 40 + lg * 8];
    f16x8 pa1 = *(const f16x8*)&ps[(l15 + 16) * 40 + lg * 8];
    #pragma unroll
    for (int nf = 0; nf < 4; ++nf) {
      f16x8 bb = *(const f16x8*)&vb[(nf * 16 + l15) * 48 + lg * 8];
      ov[0][nf] = MFMA16(pa0, bb, ov[0][nf]);
      ov[1][nf] = MFMA16(pa1, bb, ov[1][nf]);
    }
    // scatter vhat -> vh rows (tokens 4sq..4sq+3), dm = (w'&7)*64 + e
    #pragma unroll
    for (int mf = 0; mf < 2; ++mf)
      #pragma unroll
      for (int nf = 0; nf < 4; ++nf)
        #pragma unroll
        for (int r = 0; r < 4; ++r) {
          const int wp = lg * 4 + r + 16 * mf;
          const int e  = nf * 16 + l15;
          sm.xv[4 * sq + (wp >> 3)][(wp & 7) * 64 + e] = f2h(ov[mf][nf][r]);
        }
  }
  __syncthreads();

  // ---- Phase 4: out-proj, 64 cols/wave, quarter double-buffered, nt stores ----
  {
    const int nb = wv * 64;
    const _Float16* wr[4];
    #pragma unroll
    for (int nf = 0; nf < 4; ++nf)
      wr[nf] = (const _Float16*)&wo[(size_t)(nb + nf * 16 + l15) * 512 + lg * 8];
    f32x4 oa[2][4];
    #pragma unroll
    for (int a_ = 0; a_ < 2; ++a_)
      #pragma unroll
      for (int b_ = 0; b_ < 4; ++b_) oa[a_][b_] = zz;
    f16x8 wb[2][16];
    #pragma unroll
    for (int kk = 0; kk < 4; ++kk)
      #pragma unroll
      for (int nf = 0; nf < 4; ++nf)
        wb[0][kk * 4 + nf] = *(const f16x8*)(wr[nf] + kk * 32);
    #pragma unroll
    for (int qq = 0; qq < 4; ++qq) {
      if (qq < 3) {
        #pragma unroll
        for (int kk = 0; kk < 4; ++kk)
          #pragma unroll
          for (int nf = 0; nf < 4; ++nf)
            wb[(qq + 1) & 1][kk * 4 + nf] =
              *(const f16x8*)(wr[nf] + (qq + 1) * 128 + kk * 32);
      }
      #pragma unroll
      for (int kk = 0; kk < 4; ++kk) {
        const int k = qq * 4 + kk;
        f16x8 a0 = *(const f16x8*)&sm.xv[l15][k * 32 + lg * 8];
        f16x8 a1 = *(const f16x8*)&sm.xv[l15 + 16][k * 32 + lg * 8];
        #pragma unroll
        for (int nf = 0; nf < 4; ++nf) {
          oa[0][nf] = MFMA16(a0, wb[qq & 1][kk * 4 + nf], oa[0][nf]);
          oa[1][nf] = MFMA16(a1, wb[qq & 1][kk * 4 + nf], oa[1][nf]);
        }
      }
    }
    float* outp = out + slab * (32 * 512);
    #pragma unroll
    for (int nf = 0; nf < 4; ++nf) {
      const int n = nb + nf * 16 + l15;
      const float bias = bout[n];
      #pragma unroll
      for (int mf = 0; mf < 2; ++mf)
        #pragma unroll
        for (int r = 0; r < 4; ++r) {
          const int w = lg * 4 + r + 16 * mf;
          __builtin_nontemporal_store(oa[mf][nf][r] + bias,
                                      &outp[(size_t)w * 512 + n]);
        }
    }
  }
}

extern "C" void kernel_launch(void* const* d_in, const int* in_sizes, int n_in,
                              void* d_out, int out_size, void* d_ws, size_t ws_size,
                              hipStream_t stream) {
  const float* x     = (const float*)d_in[0];
  const float* gamma = (const float*)d_in[1];
  const float* beta  = (const float*)d_in[2];
  const float* Wqkv  = (const float*)d_in[3];
  const float* Wout  = (const float*)d_in[4];
  const float* bout  = (const float*)d_in[5];
  float* out = (float*)d_out;

  unsigned short* wq = (unsigned short*)d_ws;          // 1536*512 fp16
  unsigned short* wo = wq + 1536 * 512;                // 512*512 fp16

  prep_w<<<256, 512, 0, stream>>>(Wqkv, Wout, wq, wo);
  fused_attn<<<1024, 512, 0, stream>>>(x, gamma, beta, wq, wo, bout, out);
}

// Round 10
// 221.435 us; speedup vs baseline: 1.7327x; 1.7327x over previous
//
#include <hip/hip_runtime.h>

// Shapes: B=4, C=16, D=16, W=32, DM=512, H=8, HD=64. 1024 slabs of 32 tokens.
// Sequence (b,h,c',d') <-> slab (b, c=2h+(c'>>3), d=2(c'&7)+(d'>>3)), j=d'&7:
//   tokens w = 4j..4j+3; position w' = (w&3)*8 + t uses qkv cols [t*192, t*192+192).
// vhat inverse: token (c,d,w), dm = t*64 + e from position w'=(w&3)*8+t of seq j=w>>2.
//
// R2: bf16 -> fp16 (absmax 0.0322 -> 0.0039, passes).
// R3: Occ 11.8%, MfmaUtil 8% -> latency-bound. R4/R5: 512 thr -> Occ 23%, 300us.
// R5/R7: VGPR=88 twice -> compiler sinks register prefetch to uses regardless of
//        source structure; nt-stores amplified WRITE (89MB vs 67MB out) -> revert.
// R8: (a) fragment-major weight layout: prep_w emits 1KB fragment blocks
//     FB(T,S)[ln*16B] = W[S*32+(ln>>4)*8+j][T*16+(ln&15)] so every B-frag load is
//     one contiguous 1KB wave-burst (was 16 scattered lines at 1KB stride);
//     (b) sched_barrier(0)-pinned double-buffer wA/wB per 4-k-step quarter:
//     [issue 16 loads q+1] SB0 [compute q] SB0 -- compiler still emits its own
//     counted vmcnt for these normal loads, only placement is pinned.

using f16x8 = __attribute__((ext_vector_type(8))) _Float16;
using u16x8 = __attribute__((ext_vector_type(8))) unsigned short;
using f32x4 = __attribute__((ext_vector_type(4))) float;
using u16x4 = __attribute__((ext_vector_type(4))) unsigned short;

#define DEVI static __device__ __forceinline__

DEVI unsigned short f2h(float x) {            // fp32 -> fp16 RNE (v_cvt_f16_f32)
  _Float16 h = (_Float16)x;
  return *(unsigned short*)&h;
}

#define MFMA16(a, b, c) __builtin_amdgcn_mfma_f32_16x16x32_f16((a), (b), (c), 0, 0, 0)
#define SB0() __builtin_amdgcn_sched_barrier(0)

// ---- weight prep: fragment-major fp16 layout ----
// qkv: 96 tiles x 16 ksteps; out: 32 x 16. One thread = one lane of one 1KB FB.
// 2048 FBs * 64 lanes / 256 = 512 blocks.
__global__ void __launch_bounds__(256, 1)
prep_w(const float* __restrict__ Wqkv, const float* __restrict__ Wout,
       unsigned short* __restrict__ wqf, unsigned short* __restrict__ wof)
{
  const int gt = blockIdx.x * 256 + threadIdx.x;
  const int fb = gt >> 6, ln = gt & 63;
  const int lg8 = (ln >> 4) * 8, l15 = ln & 15;
  const float* src; unsigned short* dst; int ld;
  if (fb < 1536) {
    const int T = fb >> 4, S = fb & 15;
    src = Wqkv + (size_t)(S * 32 + lg8) * 1536 + T * 16 + l15;
    ld = 1536; dst = wqf + (size_t)fb * 512 + ln * 8;
  } else {
    const int f2 = fb - 1536, T = f2 >> 4, S = f2 & 15;
    src = Wout + (size_t)(S * 32 + lg8) * 512 + T * 16 + l15;
    ld = 512; dst = wof + (size_t)f2 * 512 + ln * 8;
  }
  u16x8 o;
  #pragma unroll
  for (int j = 0; j < 8; ++j) o[j] = f2h(src[(size_t)j * ld]);
  *(u16x8*)dst = o;
}

// ---------------- fused LN + QKV + attention + out-proj ----------------
struct __align__(16) SMem {
  unsigned short qs[8][32][72];   // 36864 B
  unsigned short ks[8][32][72];   // 36864 B
  unsigned short vts[8][64][48];  // 49152 B
  unsigned short xv[32][520];     // 33280 B  (xs during QKV, vh during out-proj)
};
static_assert(sizeof(SMem) == 156160, "LDS size");

// 16 frag loads for quarter q (4 ksteps x 4 tiles), each a contiguous 1KB burst
#define LOADQ(W, q) do { const int _o = (q) * 4 * 512;                         \
  W[0]  = *(const f16x8*)(b0 + _o);        W[1]  = *(const f16x8*)(b1 + _o);   \
  W[2]  = *(const f16x8*)(b2 + _o);        W[3]  = *(const f16x8*)(b3 + _o);   \
  W[4]  = *(const f16x8*)(b0 + _o + 512);  W[5]  = *(const f16x8*)(b1 + _o + 512);  \
  W[6]  = *(const f16x8*)(b2 + _o + 512);  W[7]  = *(const f16x8*)(b3 + _o + 512);  \
  W[8]  = *(const f16x8*)(b0 + _o + 1024); W[9]  = *(const f16x8*)(b1 + _o + 1024); \
  W[10] = *(const f16x8*)(b2 + _o + 1024); W[11] = *(const f16x8*)(b3 + _o + 1024); \
  W[12] = *(const f16x8*)(b0 + _o + 1536); W[13] = *(const f16x8*)(b1 + _o + 1536); \
  W[14] = *(const f16x8*)(b2 + _o + 1536); W[15] = *(const f16x8*)(b3 + _o + 1536); \
} while (0)

#define MMAQ(ACC, W, q) do {                                                   \
  _Pragma("unroll")                                                            \
  for (int kk = 0; kk < 4; ++kk) {                                             \
    const int k = (q) * 4 + kk;                                                \
    f16x8 a0 = *(const f16x8*)&sm.xv[l15][k * 32 + lg * 8];                    \
    f16x8 a1 = *(const f16x8*)&sm.xv[l15 + 16][k * 32 + lg * 8];               \
    _Pragma("unroll")                                                          \
    for (int nf = 0; nf < 4; ++nf) {                                           \
      ACC[0][nf] = MFMA16(a0, W[kk * 4 + nf], ACC[0][nf]);                     \
      ACC[1][nf] = MFMA16(a1, W[kk * 4 + nf], ACC[1][nf]);                     \
    }                                                                          \
  }                                                                            \
} while (0)

__global__ void __launch_bounds__(512, 2)
fused_attn(const float* __restrict__ x, const float* __restrict__ gamma,
           const float* __restrict__ beta,
           const unsigned short* __restrict__ wqf,  // frag-major W_qkv
           const unsigned short* __restrict__ wof,  // frag-major W_out
           const float* __restrict__ bout, float* __restrict__ out)
{
  __shared__ SMem sm;
  const int tid = threadIdx.x;
  const int wv  = tid >> 6;        // wave 0..7
  const int ln  = tid & 63;
  const int l15 = ln & 15;
  const int lg  = ln >> 4;         // lane group 0..3
  const size_t slab = blockIdx.x;  // ((b*16)+c)*16+d
  const float* xblk = x + slab * (32 * 512);
  const f32x4 zz = {0.f, 0.f, 0.f, 0.f};

  // ---- Phase 1: LayerNorm -> xs (fp16), 4 tokens per wave, nt loads ----
  {
    const f32x4* gp = (const f32x4*)gamma;
    const f32x4* bp = (const f32x4*)beta;
    f32x4 g0 = gp[ln], g1 = gp[64 + ln];
    f32x4 b0 = bp[ln], b1 = bp[64 + ln];
    f32x4 v[8];
    #pragma unroll
    for (int i = 0; i < 4; ++i) {          // all 8 loads in flight first
      const f32x4* xp = (const f32x4*)(xblk + (wv * 4 + i) * 512);
      v[2 * i]     = __builtin_nontemporal_load(xp + ln);
      v[2 * i + 1] = __builtin_nontemporal_load(xp + 64 + ln);
    }
    #pragma unroll
    for (int i = 0; i < 4; ++i) {
      int w = wv * 4 + i;
      f32x4 v0 = v[2 * i], v1 = v[2 * i + 1];
      float s  = v0.x + v0.y + v0.z + v0.w + v1.x + v1.y + v1.z + v1.w;
      float s2 = v0.x*v0.x + v0.y*v0.y + v0.z*v0.z + v0.w*v0.w
               + v1.x*v1.x + v1.y*v1.y + v1.z*v1.z + v1.w*v1.w;
      #pragma unroll
      for (int d2 = 1; d2 < 64; d2 <<= 1) {
        s  += __shfl_xor(s, d2);
        s2 += __shfl_xor(s2, d2);
      }
      float mean = s * (1.f / 512.f);
      float var  = s2 * (1.f / 512.f) - mean * mean;
      float rstd = rsqrtf(var + 1e-5f);
      u16x4 o0, o1;
      o0.x = f2h((v0.x - mean) * rstd * g0.x + b0.x);
      o0.y = f2h((v0.y - mean) * rstd * g0.y + b0.y);
      o0.z = f2h((v0.z - mean) * rstd * g0.z + b0.z);
      o0.w = f2h((v0.w - mean) * rstd * g0.w + b0.w);
      o1.x = f2h((v1.x - mean) * rstd * g1.x + b1.x);
      o1.y = f2h((v1.y - mean) * rstd * g1.y + b1.y);
      o1.z = f2h((v1.z - mean) * rstd * g1.z + b1.z);
      o1.w = f2h((v1.w - mean) * rstd * g1.w + b1.w);
      *(u16x4*)&sm.xv[w][ln * 4]       = o0;
      *(u16x4*)&sm.xv[w][256 + ln * 4] = o1;
    }
  }
  __syncthreads();

  // ---- Phase 2: QKV GEMM, 192 cols/wave in 3 chunks of 64 ----
  // sched_barrier-pinned double-buffered quarters (4 ksteps each)
  for (int c = 0; c < 3; ++c) {
    const int nb = wv * 192 + c * 64;
    const int Tb = wv * 12 + c * 4;                 // global 16-col tile base
    const _Float16* b0 = (const _Float16*)wqf + (size_t)(Tb + 0) * 8192 + ln * 8;
    const _Float16* b1 = (const _Float16*)wqf + (size_t)(Tb + 1) * 8192 + ln * 8;
    const _Float16* b2 = (const _Float16*)wqf + (size_t)(Tb + 2) * 8192 + ln * 8;
    const _Float16* b3 = (const _Float16*)wqf + (size_t)(Tb + 3) * 8192 + ln * 8;
    f32x4 acc[2][4];
    #pragma unroll
    for (int a_ = 0; a_ < 2; ++a_)
      #pragma unroll
      for (int b_ = 0; b_ < 4; ++b_) acc[a_][b_] = zz;
    f16x8 wA[16], wB[16];
    LOADQ(wA, 0); SB0();
    LOADQ(wB, 1); SB0(); MMAQ(acc, wA, 0); SB0();
    LOADQ(wA, 2); SB0(); MMAQ(acc, wB, 1); SB0();
    LOADQ(wB, 3); SB0(); MMAQ(acc, wA, 2); SB0();
    MMAQ(acc, wB, 3); SB0();
    // epilogue: scatter D frags (col = l15, rows = lg*4+r+16*mf) into qs/ks/vts
    #pragma unroll
    for (int mf = 0; mf < 2; ++mf) {
      #pragma unroll
      for (int nf = 0; nf < 4; ++nf) {
        const int n = nb + nf * 16 + l15;
        const int t = n / 192;
        const int off = n - t * 192;            // frag's 16 cols never cross a 64-seg
        const int sq = lg + 4 * mf;             // seq = w>>2, w = lg*4+r+16*mf
        #pragma unroll
        for (int r = 0; r < 4; ++r) {
          const unsigned short bv = f2h(acc[mf][nf][r]);
          const int pos = r * 8 + t;            // w&3 == r
          if (off < 64)       sm.qs[sq][pos][off]            = bv;
          else if (off < 128) sm.ks[sq][pos][off - 64]       = bv;
          else                sm.vts[sq][off - 128][pos]     = bv;
        }
      }
    }
  }
  __syncthreads();

  // ---- Phase 3: attention, 1 sequence per wave ----
  {
    const int sq = wv;
    unsigned short* ps = &sm.qs[sq][0][0];      // [32][40] overlay on dead q-buffer
    const unsigned short* qb = &sm.qs[sq][0][0];
    const unsigned short* kb = &sm.ks[sq][0][0];
    const unsigned short* vb = &sm.vts[sq][0][0];
    f32x4 sc[2][2] = {{zz, zz}, {zz, zz}};
    #pragma unroll
    for (int k2 = 0; k2 < 2; ++k2) {            // K=64 over e
      f16x8 a0 = *(const f16x8*)&qb[l15 * 72 + k2 * 32 + lg * 8];
      f16x8 a1 = *(const f16x8*)&qb[(l15 + 16) * 72 + k2 * 32 + lg * 8];
      f16x8 b0 = *(const f16x8*)&kb[l15 * 72 + k2 * 32 + lg * 8];
      f16x8 b1 = *(const f16x8*)&kb[(l15 + 16) * 72 + k2 * 32 + lg * 8];
      sc[0][0] = MFMA16(a0, b0, sc[0][0]);
      sc[0][1] = MFMA16(a0, b1, sc[0][1]);
      sc[1][0] = MFMA16(a1, b0, sc[1][0]);
      sc[1][1] = MFMA16(a1, b1, sc[1][1]);
    }
    // softmax over 32 cols; row r lives in one 16-lane group (cols l15, l15+16)
    #pragma unroll
    for (int mf = 0; mf < 2; ++mf) {
      #pragma unroll
      for (int r = 0; r < 4; ++r) {
        float s0 = sc[mf][0][r] * 8.f;          // reference MULTIPLIES by sqrt(64)
        float s1 = sc[mf][1][r] * 8.f;
        float m = fmaxf(s0, s1);
        #pragma unroll
        for (int d2 = 1; d2 < 16; d2 <<= 1) m = fmaxf(m, __shfl_xor(m, d2));
        float p0 = expf(s0 - m), p1 = expf(s1 - m);
        float sum = p0 + p1;
        #pragma unroll
        for (int d2 = 1; d2 < 16; d2 <<= 1) sum += __shfl_xor(sum, d2);
        float inv = 1.f / sum;
        const int row = lg * 4 + r + 16 * mf;
        ps[row * 40 + l15]      = f2h(p0 * inv);
        ps[row * 40 + l15 + 16] = f2h(p1 * inv);
      }
    }
    // PV: A = P (via LDS transpose), B = V^T rows -> 16B contiguous reads
    f32x4 ov[2][4] = {{zz, zz, zz, zz}, {zz, zz, zz, zz}};
    f16x8 pa0 = *(const f16x8*)&ps[l15 * 40 + lg * 8];
    f16x8 pa1 = *(const f16x8*)&ps[(l15 + 16) * 40 + lg * 8];
    #pragma unroll
    for (int nf = 0; nf < 4; ++nf) {
      f16x8 bb = *(const f16x8*)&vb[(nf * 16 + l15) * 48 + lg * 8];
      ov[0][nf] = MFMA16(pa0, bb, ov[0][nf]);
      ov[1][nf] = MFMA16(pa1, bb, ov[1][nf]);
    }
    // scatter vhat -> vh rows (tokens 4sq..4sq+3), dm = (w'&7)*64 + e
    #pragma unroll
    for (int mf = 0; mf < 2; ++mf)
      #pragma unroll
      for (int nf = 0; nf < 4; ++nf)
        #pragma unroll
        for (int r = 0; r < 4; ++r) {
          const int wp = lg * 4 + r + 16 * mf;
          const int e  = nf * 16 + l15;
          sm.xv[4 * sq + (wp >> 3)][(wp & 7) * 64 + e] = f2h(ov[mf][nf][r]);
        }
  }
  __syncthreads();

  // ---- Phase 4: out-proj, 64 cols/wave, pinned double-buffer, plain stores ----
  {
    const int nb = wv * 64;
    const _Float16* b0 = (const _Float16*)wof + (size_t)(wv * 4 + 0) * 8192 + ln * 8;
    const _Float16* b1 = (const _Float16*)wof + (size_t)(wv * 4 + 1) * 8192 + ln * 8;
    const _Float16* b2 = (const _Float16*)wof + (size_t)(wv * 4 + 2) * 8192 + ln * 8;
    const _Float16* b3 = (const _Float16*)wof + (size_t)(wv * 4 + 3) * 8192 + ln * 8;
    f32x4 oa[2][4];
    #pragma unroll
    for (int a_ = 0; a_ < 2; ++a_)
      #pragma unroll
      for (int b_ = 0; b_ < 4; ++b_) oa[a_][b_] = zz;
    f16x8 wA[16], wB[16];
    LOADQ(wA, 0); SB0();
    LOADQ(wB, 1); SB0(); MMAQ(oa, wA, 0); SB0();
    LOADQ(wA, 2); SB0(); MMAQ(oa, wB, 1); SB0();
    LOADQ(wB, 3); SB0(); MMAQ(oa, wA, 2); SB0();
    MMAQ(oa, wB, 3); SB0();
    float* outp = out + slab * (32 * 512);
    #pragma unroll
    for (int nf = 0; nf < 4; ++nf) {
      const int n = nb + nf * 16 + l15;
      const float bias = bout[n];
      #pragma unroll
      for (int mf = 0; mf < 2; ++mf)
        #pragma unroll
        for (int r = 0; r < 4; ++r) {
          const int w = lg * 4 + r + 16 * mf;
          outp[(size_t)w * 512 + n] = oa[mf][nf][r] + bias;
        }
    }
  }
}

extern "C" void kernel_launch(void* const* d_in, const int* in_sizes, int n_in,
                              void* d_out, int out_size, void* d_ws, size_t ws_size,
                              hipStream_t stream) {
  const float* x     = (const float*)d_in[0];
  const float* gamma = (const float*)d_in[1];
  const float* beta  = (const float*)d_in[2];
  const float* Wqkv  = (const float*)d_in[3];
  const float* Wout  = (const float*)d_in[4];
  const float* bout  = (const float*)d_in[5];
  float* out = (float*)d_out;

  unsigned short* wqf = (unsigned short*)d_ws;         // 1536 FBs * 512 fp16
  unsigned short* wof = wqf + 1536 * 512;              // 512 FBs * 512 fp16

  prep_w<<<512, 256, 0, stream>>>(Wqkv, Wout, wqf, wof);
  fused_attn<<<1024, 512, 0, stream>>>(x, gamma, beta, wqf, wof, bout, out);
}

// Round 13
// 220.008 us; speedup vs baseline: 1.7439x; 1.0065x over previous
//
#include <hip/hip_runtime.h>

// Shapes: B=4, C=16, D=16, W=32, DM=512, H=8, HD=64. 1024 slabs of 32 tokens.
// Sequence (b,h,c',d') <-> slab (b, c=2h+(c'>>3), d=2(c'&7)+(d'>>3)), j=d'&7:
//   tokens w = 4j..4j+3; position w' = (w&3)*8 + t uses qkv cols [t*192, t*192+192).
// vhat inverse: token (c,d,w), dm = t*64 + e from position w'=(w&3)*8+t of seq j=w>>2.
//
// R2: bf16 -> fp16 (absmax 0.0039). R3: latency-bound. R4/R5: 512 thr, Occ 23%.
// R8/R10: fragment-major weights (1KB wave-bursts) + SB0 pinning: 295 -> 156us,
//   but VGPR=116 => only ONE buffer materialized (IR pass merged wA/wB pre-sched).
// R11: inline-asm global_load_dwordx4 + hand-counted s_waitcnt vmcnt(16/0):
//   asm volatile loads can't be merged/sunk; 32 dsts forced live; "memory"
//   clobbers keep compiler VMEM (bias/out) outside the counted region; SB0
//   after each waitcnt stops MFMA hoisting (rule #18). L2 floor ~58us.

using f16x8 = __attribute__((ext_vector_type(8))) _Float16;
using u16x8 = __attribute__((ext_vector_type(8))) unsigned short;
using f32x4 = __attribute__((ext_vector_type(4))) float;
using u16x4 = __attribute__((ext_vector_type(4))) unsigned short;

#define DEVI static __device__ __forceinline__

DEVI unsigned short f2h(float x) {            // fp32 -> fp16 RNE (v_cvt_f16_f32)
  _Float16 h = (_Float16)x;
  return *(unsigned short*)&h;
}

#define MFMA16(a, b, c) __builtin_amdgcn_mfma_f32_16x16x32_f16((a), (b), (c), 0, 0, 0)
#define SB0() __builtin_amdgcn_sched_barrier(0)

// ---- weight prep: fragment-major fp16 layout (unchanged from R8) ----
__global__ void __launch_bounds__(256, 1)
prep_w(const float* __restrict__ Wqkv, const float* __restrict__ Wout,
       unsigned short* __restrict__ wqf, unsigned short* __restrict__ wof)
{
  const int gt = blockIdx.x * 256 + threadIdx.x;
  const int fb = gt >> 6, ln = gt & 63;
  const int lg8 = (ln >> 4) * 8, l15 = ln & 15;
  const float* src; unsigned short* dst; int ld;
  if (fb < 1536) {
    const int T = fb >> 4, S = fb & 15;
    src = Wqkv + (size_t)(S * 32 + lg8) * 1536 + T * 16 + l15;
    ld = 1536; dst = wqf + (size_t)fb * 512 + ln * 8;
  } else {
    const int f2 = fb - 1536, T = f2 >> 4, S = f2 & 15;
    src = Wout + (size_t)(S * 32 + lg8) * 512 + T * 16 + l15;
    ld = 512; dst = wof + (size_t)f2 * 512 + ln * 8;
  }
  u16x8 o;
  #pragma unroll
  for (int j = 0; j < 8; ++j) o[j] = f2h(src[(size_t)j * ld]);
  *(u16x8*)dst = o;
}

// ---------------- fused LN + QKV + attention + out-proj ----------------
struct __align__(16) SMem {
  unsigned short qs[8][32][72];   // 36864 B
  unsigned short ks[8][32][72];   // 36864 B
  unsigned short vts[8][64][48];  // 49152 B
  unsigned short xv[32][520];     // 33280 B  (xs during QKV, vh during out-proj)
};
static_assert(sizeof(SMem) == 156160, "LDS size");

// one asm load: 16B/lane contiguous burst, dst forced live until its MFMA use
#define AL(dst, p, OFF)                                                        \
  asm volatile("global_load_dwordx4 %0, %1, off " OFF                          \
               : "=&v"(dst) : "v"(p) : "memory")

// 16 loads for quarter q: W[kk*4+t] <- tile t, kstep q*4+kk
#define ALOADQ(W, q) do {                                                      \
  const _Float16* _p0 = b0 + (q) * 2048;                                       \
  const _Float16* _p1 = b1 + (q) * 2048;                                       \
  const _Float16* _p2 = b2 + (q) * 2048;                                       \
  const _Float16* _p3 = b3 + (q) * 2048;                                       \
  AL(W[0],  _p0, "");             AL(W[1],  _p1, "");                          \
  AL(W[2],  _p2, "");             AL(W[3],  _p3, "");                          \
  AL(W[4],  _p0, "offset:1024");  AL(W[5],  _p1, "offset:1024");               \
  AL(W[6],  _p2, "offset:1024");  AL(W[7],  _p3, "offset:1024");               \
  AL(W[8],  _p0, "offset:2048");  AL(W[9],  _p1, "offset:2048");               \
  AL(W[10], _p2, "offset:2048");  AL(W[11], _p3, "offset:2048");               \
  AL(W[12], _p0, "offset:3072");  AL(W[13], _p1, "offset:3072");               \
  AL(W[14], _p2, "offset:3072");  AL(W[15], _p3, "offset:3072");               \
} while (0)

#define WAIT16() do { asm volatile("s_waitcnt vmcnt(16)" ::: "memory"); SB0(); } while (0)
#define WAIT0()  do { asm volatile("s_waitcnt vmcnt(0)"  ::: "memory"); SB0(); } while (0)

#define MMAQ(ACC, W, q) do {                                                   \
  _Pragma("unroll")                                                            \
  for (int kk = 0; kk < 4; ++kk) {                                             \
    const int k = (q) * 4 + kk;                                                \
    f16x8 a0 = *(const f16x8*)&sm.xv[l15][k * 32 + lg * 8];                    \
    f16x8 a1 = *(const f16x8*)&sm.xv[l15 + 16][k * 32 + lg * 8];               \
    _Pragma("unroll")                                                          \
    for (int nf = 0; nf < 4; ++nf) {                                           \
      ACC[0][nf] = MFMA16(a0, W[kk * 4 + nf], ACC[0][nf]);                     \
      ACC[1][nf] = MFMA16(a1, W[kk * 4 + nf], ACC[1][nf]);                     \
    }                                                                          \
  }                                                                            \
} while (0)

// full double-buffered 16-kstep pass over one 64-col chunk
#define GEMM_CHUNK(ACC) do {                                                   \
  f16x8 wA[16], wB[16];                                                        \
  ALOADQ(wA, 0);                                                               \
  ALOADQ(wB, 1);                                                               \
  WAIT16(); MMAQ(ACC, wA, 0);                                                  \
  ALOADQ(wA, 2);                                                               \
  WAIT16(); MMAQ(ACC, wB, 1);                                                  \
  ALOADQ(wB, 3);                                                               \
  WAIT16(); MMAQ(ACC, wA, 2);                                                  \
  WAIT0();  MMAQ(ACC, wB, 3);                                                  \
} while (0)

__global__ void __launch_bounds__(512, 2)
fused_attn(const float* __restrict__ x, const float* __restrict__ gamma,
           const float* __restrict__ beta,
           const unsigned short* __restrict__ wqf,  // frag-major W_qkv
           const unsigned short* __restrict__ wof,  // frag-major W_out
           const float* __restrict__ bout, float* __restrict__ out)
{
  __shared__ SMem sm;
  const int tid = threadIdx.x;
  const int wv  = tid >> 6;        // wave 0..7
  const int ln  = tid & 63;
  const int l15 = ln & 15;
  const int lg  = ln >> 4;         // lane group 0..3
  const size_t slab = blockIdx.x;  // ((b*16)+c)*16+d
  const float* xblk = x + slab * (32 * 512);
  const f32x4 zz = {0.f, 0.f, 0.f, 0.f};

  // ---- Phase 1: LayerNorm -> xs (fp16), 4 tokens per wave, nt loads ----
  {
    const f32x4* gp = (const f32x4*)gamma;
    const f32x4* bp = (const f32x4*)beta;
    f32x4 g0 = gp[ln], g1 = gp[64 + ln];
    f32x4 b0 = bp[ln], b1 = bp[64 + ln];
    f32x4 v[8];
    #pragma unroll
    for (int i = 0; i < 4; ++i) {          // all 8 loads in flight first
      const f32x4* xp = (const f32x4*)(xblk + (wv * 4 + i) * 512);
      v[2 * i]     = __builtin_nontemporal_load(xp + ln);
      v[2 * i + 1] = __builtin_nontemporal_load(xp + 64 + ln);
    }
    #pragma unroll
    for (int i = 0; i < 4; ++i) {
      int w = wv * 4 + i;
      f32x4 v0 = v[2 * i], v1 = v[2 * i + 1];
      float s  = v0.x + v0.y + v0.z + v0.w + v1.x + v1.y + v1.z + v1.w;
      float s2 = v0.x*v0.x + v0.y*v0.y + v0.z*v0.z + v0.w*v0.w
               + v1.x*v1.x + v1.y*v1.y + v1.z*v1.z + v1.w*v1.w;
      #pragma unroll
      for (int d2 = 1; d2 < 64; d2 <<= 1) {
        s  += __shfl_xor(s, d2);
        s2 += __shfl_xor(s2, d2);
      }
      float mean = s * (1.f / 512.f);
      float var  = s2 * (1.f / 512.f) - mean * mean;
      float rstd = rsqrtf(var + 1e-5f);
      u16x4 o0, o1;
      o0.x = f2h((v0.x - mean) * rstd * g0.x + b0.x);
      o0.y = f2h((v0.y - mean) * rstd * g0.y + b0.y);
      o0.z = f2h((v0.z - mean) * rstd * g0.z + b0.z);
      o0.w = f2h((v0.w - mean) * rstd * g0.w + b0.w);
      o1.x = f2h((v1.x - mean) * rstd * g1.x + b1.x);
      o1.y = f2h((v1.y - mean) * rstd * g1.y + b1.y);
      o1.z = f2h((v1.z - mean) * rstd * g1.z + b1.z);
      o1.w = f2h((v1.w - mean) * rstd * g1.w + b1.w);
      *(u16x4*)&sm.xv[w][ln * 4]       = o0;
      *(u16x4*)&sm.xv[w][256 + ln * 4] = o1;
    }
  }
  __syncthreads();

  // ---- Phase 2: QKV GEMM, 192 cols/wave in 3 chunks of 64, asm-DB ----
  for (int c = 0; c < 3; ++c) {
    const int nb = wv * 192 + c * 64;
    const int Tb = wv * 12 + c * 4;                 // global 16-col tile base
    const _Float16* b0 = (const _Float16*)wqf + (size_t)(Tb + 0) * 8192 + ln * 8;
    const _Float16* b1 = (const _Float16*)wqf + (size_t)(Tb + 1) * 8192 + ln * 8;
    const _Float16* b2 = (const _Float16*)wqf + (size_t)(Tb + 2) * 8192 + ln * 8;
    const _Float16* b3 = (const _Float16*)wqf + (size_t)(Tb + 3) * 8192 + ln * 8;
    f32x4 acc[2][4];
    #pragma unroll
    for (int a_ = 0; a_ < 2; ++a_)
      #pragma unroll
      for (int b_ = 0; b_ < 4; ++b_) acc[a_][b_] = zz;
    GEMM_CHUNK(acc);
    // epilogue: scatter D frags (col = l15, rows = lg*4+r+16*mf) into qs/ks/vts
    #pragma unroll
    for (int mf = 0; mf < 2; ++mf) {
      #pragma unroll
      for (int nf = 0; nf < 4; ++nf) {
        const int n = nb + nf * 16 + l15;
        const int t = n / 192;
        const int off = n - t * 192;            // frag's 16 cols never cross a 64-seg
        const int sq = lg + 4 * mf;             // seq = w>>2, w = lg*4+r+16*mf
        #pragma unroll
        for (int r = 0; r < 4; ++r) {
          const unsigned short bv = f2h(acc[mf][nf][r]);
          const int pos = r * 8 + t;            // w&3 == r
          if (off < 64)       sm.qs[sq][pos][off]            = bv;
          else if (off < 128) sm.ks[sq][pos][off - 64]       = bv;
          else                sm.vts[sq][off - 128][pos]     = bv;
        }
      }
    }
  }
  __syncthreads();

  // ---- Phase 3: attention, 1 sequence per wave ----
  {
    const int sq = wv;
    unsigned short* ps = &sm.qs[sq][0][0];      // [32][40] overlay on dead q-buffer
    const unsigned short* qb = &sm.qs[sq][0][0];
    const unsigned short* kb = &sm.ks[sq][0][0];
    const unsigned short* vb = &sm.vts[sq][0][0];
    f32x4 sc[2][2] = {{zz, zz}, {zz, zz}};
    #pragma unroll
    for (int k2 = 0; k2 < 2; ++k2) {            // K=64 over e
      f16x8 a0 = *(const f16x8*)&qb[l15 * 72 + k2 * 32 + lg * 8];
      f16x8 a1 = *(const f16x8*)&qb[(l15 + 16) * 72 + k2 * 32 + lg * 8];
      f16x8 b0 = *(const f16x8*)&kb[l15 * 72 + k2 * 32 + lg * 8];
      f16x8 b1 = *(const f16x8*)&kb[(l15 + 16) * 72 + k2 * 32 + lg * 8];
      sc[0][0] = MFMA16(a0, b0, sc[0][0]);
      sc[0][1] = MFMA16(a0, b1, sc[0][1]);
      sc[1][0] = MFMA16(a1, b0, sc[1][0]);
      sc[1][1] = MFMA16(a1, b1, sc[1][1]);
    }
    // softmax over 32 cols; row r lives in one 16-lane group (cols l15, l15+16)
    #pragma unroll
    for (int mf = 0; mf < 2; ++mf) {
      #pragma unroll
      for (int r = 0; r < 4; ++r) {
        float s0 = sc[mf][0][r] * 8.f;          // reference MULTIPLIES by sqrt(64)
        float s1 = sc[mf][1][r] * 8.f;
        float m = fmaxf(s0, s1);
        #pragma unroll
        for (int d2 = 1; d2 < 16; d2 <<= 1) m = fmaxf(m, __shfl_xor(m, d2));
        float p0 = expf(s0 - m), p1 = expf(s1 - m);
        float sum = p0 + p1;
        #pragma unroll
        for (int d2 = 1; d2 < 16; d2 <<= 1) sum += __shfl_xor(sum, d2);
        float inv = 1.f / sum;
        const int row = lg * 4 + r + 16 * mf;
        ps[row * 40 + l15]      = f2h(p0 * inv);
        ps[row * 40 + l15 + 16] = f2h(p1 * inv);
      }
    }
    // PV: A = P (via LDS transpose), B = V^T rows -> 16B contiguous reads
    f32x4 ov[2][4] = {{zz, zz, zz, zz}, {zz, zz, zz, zz}};
    f16x8 pa0 = *(const f16x8*)&ps[l15 * 40 + lg * 8];
    f16x8 pa1 = *(const f16x8*)&ps[(l15 + 16) * 40 + lg * 8];
    #pragma unroll
    for (int nf = 0; nf < 4; ++nf) {
      f16x8 bb = *(const f16x8*)&vb[(nf * 16 + l15) * 48 + lg * 8];
      ov[0][nf] = MFMA16(pa0, bb, ov[0][nf]);
      ov[1][nf] = MFMA16(pa1, bb, ov[1][nf]);
    }
    // scatter vhat -> vh rows (tokens 4sq..4sq+3), dm = (w'&7)*64 + e
    #pragma unroll
    for (int mf = 0; mf < 2; ++mf)
      #pragma unroll
      for (int nf = 0; nf < 4; ++nf)
        #pragma unroll
        for (int r = 0; r < 4; ++r) {
          const int wp = lg * 4 + r + 16 * mf;
          const int e  = nf * 16 + l15;
          sm.xv[4 * sq + (wp >> 3)][(wp & 7) * 64 + e] = f2h(ov[mf][nf][r]);
        }
  }
  __syncthreads();

  // ---- Phase 4: out-proj, 64 cols/wave, asm-DB, plain stores ----
  {
    const int nb = wv * 64;
    const _Float16* b0 = (const _Float16*)wof + (size_t)(wv * 4 + 0) * 8192 + ln * 8;
    const _Float16* b1 = (const _Float16*)wof + (size_t)(wv * 4 + 1) * 8192 + ln * 8;
    const _Float16* b2 = (const _Float16*)wof + (size_t)(wv * 4 + 2) * 8192 + ln * 8;
    const _Float16* b3 = (const _Float16*)wof + (size_t)(wv * 4 + 3) * 8192 + ln * 8;
    f32x4 oa[2][4];
    #pragma unroll
    for (int a_ = 0; a_ < 2; ++a_)
      #pragma unroll
      for (int b_ = 0; b_ < 4; ++b_) oa[a_][b_] = zz;
    GEMM_CHUNK(oa);
    // bias load + stores sit AFTER the final vmcnt(0) and cannot hoist across
    // the "memory"-clobbered asm region -> counted waits stay exact.
    float* outp = out + slab * (32 * 512);
    #pragma unroll
    for (int nf = 0; nf < 4; ++nf) {
      const int n = nb + nf * 16 + l15;
      const float bias = bout[n];
      #pragma unroll
      for (int mf = 0; mf < 2; ++mf)
        #pragma unroll
        for (int r = 0; r < 4; ++r) {
          const int w = lg * 4 + r + 16 * mf;
          outp[(size_t)w * 512 + n] = oa[mf][nf][r] + bias;
        }
    }
  }
}

extern "C" void kernel_launch(void* const* d_in, const int* in_sizes, int n_in,
                              void* d_out, int out_size, void* d_ws, size_t ws_size,
                              hipStream_t stream) {
  const float* x     = (const float*)d_in[0];
  const float* gamma = (const float*)d_in[1];
  const float* beta  = (const float*)d_in[2];
  const float* Wqkv  = (const float*)d_in[3];
  const float* Wout  = (const float*)d_in[4];
  const float* bout  = (const float*)d_in[5];
  float* out = (float*)d_out;

  unsigned short* wqf = (unsigned short*)d_ws;         // 1536 FBs * 512 fp16
  unsigned short* wof = wqf + 1536 * 512;              // 512 FBs * 512 fp16

  prep_w<<<512, 256, 0, stream>>>(Wqkv, Wout, wqf, wof);
  fused_attn<<<1024, 512, 0, stream>>>(x, gamma, beta, wqf, wof, bout, out);
}